// Round 9
// baseline (408.493 us; speedup 1.0000x reference)
//
#include <hip/hip_runtime.h>

// BinaryLinear: out = (x @ sign(w)^T) * alpha[o],  alpha = mean(|w|, axis=1)
// x: [65536,1024] f32, w: [1024,1024] f32, out: [65536,1024] f32
//
// R9: safe rebuild after R6/R8 core dumps. A direct global->reg per-lane
//     fragments via PLAIN loads (compiler-tracked), prefetch 1 K-tile ahead,
//     in-reg f32->fp16. B via global_load_lds, 2-buffer, ONE __syncthreads per
//     K-tile (m97 regime). No inline asm / raw barriers / manual vmcnt.
//     launch_bounds(512,2) -> hard 256-VGPR cap (launchability guaranteed).

typedef _Float16 half8 __attribute__((ext_vector_type(8)));
typedef _Float16 half4v __attribute__((ext_vector_type(4)));
typedef float f32x4 __attribute__((ext_vector_type(4)));

#define TOKENS 65536
#define INF 1024
#define OUTF 1024
#define BM 256
#define BN 256
#define BK 32
#define NKT 32

__device__ __forceinline__ void gload_lds16(const void* g, void* l) {
  __builtin_amdgcn_global_load_lds(
      (const __attribute__((address_space(1))) unsigned int*)g,
      (__attribute__((address_space(3))) unsigned int*)l, 16, 0, 0);
}

__device__ __forceinline__ half8 cvt8(f32x4 a, f32x4 b) {
  half8 h;
  h[0] = (_Float16)a[0]; h[1] = (_Float16)a[1];
  h[2] = (_Float16)a[2]; h[3] = (_Float16)a[3];
  h[4] = (_Float16)b[0]; h[5] = (_Float16)b[1];
  h[6] = (_Float16)b[2]; h[7] = (_Float16)b[3];
  return h;
}

// ---------------- prep: alpha + sign(fp16) ----------------
__global__ __launch_bounds__(256) void bl_prep(const float* __restrict__ w,
                                               _Float16* __restrict__ sbin,
                                               float* __restrict__ alpha) {
  const int o = blockIdx.x;
  const int tid = threadIdx.x;
  const float4 v = ((const float4*)(w + (size_t)o * INF))[tid];
  float s = fabsf(v.x) + fabsf(v.y) + fabsf(v.z) + fabsf(v.w);
  half4v h;
  h[0] = (_Float16)((v.x > 0.f) ? 1.f : ((v.x < 0.f) ? -1.f : 0.f));
  h[1] = (_Float16)((v.y > 0.f) ? 1.f : ((v.y < 0.f) ? -1.f : 0.f));
  h[2] = (_Float16)((v.z > 0.f) ? 1.f : ((v.z < 0.f) ? -1.f : 0.f));
  h[3] = (_Float16)((v.w > 0.f) ? 1.f : ((v.w < 0.f) ? -1.f : 0.f));
  *(half4v*)(sbin + (size_t)o * INF + tid * 4) = h;
#pragma unroll
  for (int off = 32; off > 0; off >>= 1) s += __shfl_down(s, off, 64);
  __shared__ float red[4];
  const int wave = tid >> 6, lane = tid & 63;
  if (lane == 0) red[wave] = s;
  __syncthreads();
  if (tid == 0) alpha[o] = (red[0] + red[1] + red[2] + red[3]) * (1.0f / 1024.0f);
}

// ---------------- GEMM ----------------
__global__ __launch_bounds__(512, 2) void bl_gemm(const float* __restrict__ x,
                                                  const _Float16* __restrict__ sbin,
                                                  const float* __restrict__ alpha,
                                                  float* __restrict__ out) {
  __shared__ _Float16 ldsB[2][BN * BK]; // 2 x 16KB = 32KB

  const int tid = threadIdx.x;
  const int lane = tid & 63;
  const int wid = tid >> 6;
  const int l15 = lane & 15;
  const int kc = lane >> 4; // 0..3
  const int wr = wid >> 1;  // 0..3 (64-row slice)
  const int wc = wid & 1;   // 0..1 (128-col slice)

  // XCD chunked swizzle: 1024 blocks -> 128 consecutive per XCD;
  // 4 consecutive wgids share a row panel (A L2 reuse on one XCD).
  const int bid = blockIdx.x;
  const int wgid = (bid & 7) * 128 + (bid >> 3);
  const int bm0 = (wgid >> 2) * BM;
  const int bn0 = (wgid & 3) * BN;

  // ---- B staging: 16KB tile = 1024 x 16B chunks; thread owns 2 chunks ----
  // LDS[row][slot s] holds source chunk s ^ ((row>>1)&3)  (involution)
  size_t bSrc[2];
  int bDst[2];
#pragma unroll
  for (int p = 0; p < 2; ++p) {
    const int ci = p * 512 + tid;
    const int row = ci >> 2;
    const int c = (ci & 3) ^ ((row >> 1) & 3);
    bSrc[p] = (size_t)(bn0 + row) * INF + c * 8; // fp16 elems (pre-swizzled src)
    bDst[p] = ci * 16;                           // linear LDS byte dest
  }
  // ---- B fragment reads: 8 n-frags; slot = kc ^ ((row>>1)&3) ----
  int bRd[8];
#pragma unroll
  for (int nf = 0; nf < 8; ++nf) {
    const int row = wc * 128 + nf * 16 + l15;
    bRd[nf] = row * 64 + ((kc ^ ((row >> 1) & 3)) << 4);
  }
  // ---- A: per-lane fragment base (lane-exact MFMA A layout) ----
  const float* aBase = x + (size_t)(bm0 + wr * 64 + l15) * INF + kc * 8;

  f32x4 acc[4][8] = {};
  f32x4 a0[4][2], a1[4][2]; // A K-tile register sets (static indexing)

#define LOADA(dst_, ko_)                                                       \
  {                                                                            \
    _Pragma("unroll") for (int mf = 0; mf < 4; ++mf) {                         \
      dst_[mf][0] = *(const f32x4*)(aBase + mf * 16384 + (ko_));               \
      dst_[mf][1] = *(const f32x4*)(aBase + mf * 16384 + (ko_) + 4);           \
    }                                                                          \
  }

#define STAGEB(buf_, tk_)                                                      \
  {                                                                            \
    gload_lds16(sbin + bSrc[0] + (size_t)(tk_)*BK, (char*)&ldsB[buf_][0] + bDst[0]); \
    gload_lds16(sbin + bSrc[1] + (size_t)(tk_)*BK, (char*)&ldsB[buf_][0] + bDst[1]); \
  }

// compute one K-tile from ldsB[buf_] and A-regs areg_ (split n-halves to
// keep only 4 live B frags)
#define COMPUTE(buf_, areg_)                                                   \
  {                                                                            \
    half8 af0 = cvt8(areg_[0][0], areg_[0][1]);                                \
    half8 af1 = cvt8(areg_[1][0], areg_[1][1]);                                \
    half8 af2 = cvt8(areg_[2][0], areg_[2][1]);                                \
    half8 af3 = cvt8(areg_[3][0], areg_[3][1]);                                \
    const char* pb_ = (const char*)&ldsB[buf_][0];                             \
    half8 b0 = *(const half8*)(pb_ + bRd[0]);                                  \
    half8 b1 = *(const half8*)(pb_ + bRd[1]);                                  \
    half8 b2 = *(const half8*)(pb_ + bRd[2]);                                  \
    half8 b3 = *(const half8*)(pb_ + bRd[3]);                                  \
    acc[0][0] = __builtin_amdgcn_mfma_f32_16x16x32_f16(af0, b0, acc[0][0], 0, 0, 0); \
    acc[1][0] = __builtin_amdgcn_mfma_f32_16x16x32_f16(af1, b0, acc[1][0], 0, 0, 0); \
    acc[2][0] = __builtin_amdgcn_mfma_f32_16x16x32_f16(af2, b0, acc[2][0], 0, 0, 0); \
    acc[3][0] = __builtin_amdgcn_mfma_f32_16x16x32_f16(af3, b0, acc[3][0], 0, 0, 0); \
    acc[0][1] = __builtin_amdgcn_mfma_f32_16x16x32_f16(af0, b1, acc[0][1], 0, 0, 0); \
    acc[1][1] = __builtin_amdgcn_mfma_f32_16x16x32_f16(af1, b1, acc[1][1], 0, 0, 0); \
    acc[2][1] = __builtin_amdgcn_mfma_f32_16x16x32_f16(af2, b1, acc[2][1], 0, 0, 0); \
    acc[3][1] = __builtin_amdgcn_mfma_f32_16x16x32_f16(af3, b1, acc[3][1], 0, 0, 0); \
    acc[0][2] = __builtin_amdgcn_mfma_f32_16x16x32_f16(af0, b2, acc[0][2], 0, 0, 0); \
    acc[1][2] = __builtin_amdgcn_mfma_f32_16x16x32_f16(af1, b2, acc[1][2], 0, 0, 0); \
    acc[2][2] = __builtin_amdgcn_mfma_f32_16x16x32_f16(af2, b2, acc[2][2], 0, 0, 0); \
    acc[3][2] = __builtin_amdgcn_mfma_f32_16x16x32_f16(af3, b2, acc[3][2], 0, 0, 0); \
    acc[0][3] = __builtin_amdgcn_mfma_f32_16x16x32_f16(af0, b3, acc[0][3], 0, 0, 0); \
    acc[1][3] = __builtin_amdgcn_mfma_f32_16x16x32_f16(af1, b3, acc[1][3], 0, 0, 0); \
    acc[2][3] = __builtin_amdgcn_mfma_f32_16x16x32_f16(af2, b3, acc[2][3], 0, 0, 0); \
    acc[3][3] = __builtin_amdgcn_mfma_f32_16x16x32_f16(af3, b3, acc[3][3], 0, 0, 0); \
    b0 = *(const half8*)(pb_ + bRd[4]);                                        \
    b1 = *(const half8*)(pb_ + bRd[5]);                                        \
    b2 = *(const half8*)(pb_ + bRd[6]);                                        \
    b3 = *(const half8*)(pb_ + bRd[7]);                                        \
    acc[0][4] = __builtin_amdgcn_mfma_f32_16x16x32_f16(af0, b0, acc[0][4], 0, 0, 0); \
    acc[1][4] = __builtin_amdgcn_mfma_f32_16x16x32_f16(af1, b0, acc[1][4], 0, 0, 0); \
    acc[2][4] = __builtin_amdgcn_mfma_f32_16x16x32_f16(af2, b0, acc[2][4], 0, 0, 0); \
    acc[3][4] = __builtin_amdgcn_mfma_f32_16x16x32_f16(af3, b0, acc[3][4], 0, 0, 0); \
    acc[0][5] = __builtin_amdgcn_mfma_f32_16x16x32_f16(af0, b1, acc[0][5], 0, 0, 0); \
    acc[1][5] = __builtin_amdgcn_mfma_f32_16x16x32_f16(af1, b1, acc[1][5], 0, 0, 0); \
    acc[2][5] = __builtin_amdgcn_mfma_f32_16x16x32_f16(af2, b1, acc[2][5], 0, 0, 0); \
    acc[3][5] = __builtin_amdgcn_mfma_f32_16x16x32_f16(af3, b1, acc[3][5], 0, 0, 0); \
    acc[0][6] = __builtin_amdgcn_mfma_f32_16x16x32_f16(af0, b2, acc[0][6], 0, 0, 0); \
    acc[1][6] = __builtin_amdgcn_mfma_f32_16x16x32_f16(af1, b2, acc[1][6], 0, 0, 0); \
    acc[2][6] = __builtin_amdgcn_mfma_f32_16x16x32_f16(af2, b2, acc[2][6], 0, 0, 0); \
    acc[3][6] = __builtin_amdgcn_mfma_f32_16x16x32_f16(af3, b2, acc[3][6], 0, 0, 0); \
    acc[0][7] = __builtin_amdgcn_mfma_f32_16x16x32_f16(af0, b3, acc[0][7], 0, 0, 0); \
    acc[1][7] = __builtin_amdgcn_mfma_f32_16x16x32_f16(af1, b3, acc[1][7], 0, 0, 0); \
    acc[2][7] = __builtin_amdgcn_mfma_f32_16x16x32_f16(af2, b3, acc[2][7], 0, 0, 0); \
    acc[3][7] = __builtin_amdgcn_mfma_f32_16x16x32_f16(af3, b3, acc[3][7], 0, 0, 0); \
  }

  // ---------------- prologue: tile 0 ----------------
  STAGEB(0, 0);
  LOADA(a0, 0);
  __syncthreads(); // compiler drains vmcnt+lgkm before barrier

  // 2x-unrolled main loop: even tile reads lds0/a0, odd reads lds1/a1
#pragma unroll 1
  for (int u = 0; u < NKT / 2; ++u) {
    const int Te = 2 * u;
    // even phase: compute tile Te; stage/load tile Te+1 into lds1/a1
    {
      STAGEB(1, Te + 1);
      LOADA(a1, (size_t)(Te + 1) * BK);
      COMPUTE(0, a0);
      __syncthreads();
    }
    // odd phase: compute tile Te+1; stage/load tile Te+2 into lds0/a0
    {
      if (Te + 2 < NKT) {
        STAGEB(0, Te + 2);
        LOADA(a0, (size_t)(Te + 2) * BK);
      }
      COMPUTE(1, a1);
      __syncthreads();
    }
  }
#undef COMPUTE
#undef STAGEB
#undef LOADA

  // ---------------- epilogue: scale by alpha[col], store f32 ----------------
  float al[8];
#pragma unroll
  for (int n = 0; n < 8; ++n) al[n] = alpha[bn0 + wc * 128 + n * 16 + l15];
#pragma unroll
  for (int mf = 0; mf < 4; ++mf) {
    const int row0 = bm0 + wr * 64 + mf * 16 + kc * 4;
#pragma unroll
    for (int n = 0; n < 8; ++n) {
      const int col = bn0 + wc * 128 + n * 16 + l15;
#pragma unroll
      for (int j = 0; j < 4; ++j)
        out[(size_t)(row0 + j) * OUTF + col] = acc[mf][n][j] * al[n];
    }
  }
}

extern "C" void kernel_launch(void* const* d_in, const int* in_sizes, int n_in,
                              void* d_out, int out_size, void* d_ws, size_t ws_size,
                              hipStream_t stream) {
  const float* x = (const float*)d_in[0];
  const float* w = (const float*)d_in[1];
  float* out = (float*)d_out;
  _Float16* sbin = (_Float16*)d_ws;                              // 2 MB
  float* alpha = (float*)((char*)d_ws + (size_t)OUTF * INF * 2); // 4 KB

  bl_prep<<<dim3(OUTF), dim3(256), 0, stream>>>(w, sbin, alpha);
  bl_gemm<<<dim3((TOKENS / BM) * (OUTF / BN)), dim3(512), 0, stream>>>(x, sbin, alpha, out);
}